// Round 2
// baseline (126.648 us; speedup 1.0000x reference)
//
#include <hip/hip_runtime.h>
#include <cstdint>
#include <cstddef>

#define CIN   256
#define COUT  256
#define CMID  64
#define H     64
#define W     64
#define HO    128
#define WO    128
#define BATCH 4

typedef unsigned short u16;
typedef unsigned int   u32;
typedef __attribute__((ext_vector_type(8))) __bf16 bf16x8;
typedef __attribute__((ext_vector_type(4))) float f32x4;

// Packed layouts (granule = 8 bf16 = 16 B, lane-contiguous):
//   Xt [b][y(65)][s=kc*4+q (32)][x(65)][8ci]   row = 16640 u16
//   X2t[b][y(65)][s=kc2*4+q (8)][x(65)][8cm]   row = 4160 u16
//   WPH[t(9)][kc(8)][q(4)][co(256)][8ci]
//   WPL[t(9)][kc2(2)][q(4)][co(256)][8cm]
// y==64 zero guard row; x==64 zero guard granule.
#define XT_ROW  16640
#define X2_ROW  4160

#define AS1 __attribute__((address_space(1)))
#define AS3 __attribute__((address_space(3)))

// global->LDS direct 16B copy; LDS dst is wave-uniform base, HW adds lane*16.
__device__ __forceinline__ void g2l16(const void* g, const void* l) {
    __builtin_amdgcn_global_load_lds((const AS1 u32*)(uintptr_t)g,
                                     (AS3 u32*)(u32)(uintptr_t)l, 16, 0, 0);
}

__device__ __forceinline__ u16 f2bf(float f) {
    u32 u = __builtin_bit_cast(u32, f);
    u += 0x7fffu + ((u >> 16) & 1u);          // RNE
    return (u16)(u >> 16);
}

// ---------------------------------------------------------------------------
// Fused prep (grid 332 = 260 input blocks + 72 weight-pack blocks).
// ---------------------------------------------------------------------------
__global__ __launch_bounds__(256) void k_prep(const float* __restrict__ inx,
                                              const float* __restrict__ w1,
                                              const float* __restrict__ b1,
                                              const float* __restrict__ wH,
                                              const float* __restrict__ wL,
                                              u16* __restrict__ Xt,
                                              u16* __restrict__ X2t,
                                              u16* __restrict__ WPH,
                                              u16* __restrict__ WPL) {
    __shared__ __align__(16) u16 sX[32 * 64 * 8];     // 32 KiB [s][x][8ci]
    __shared__ __align__(16) u16 sW1[8 * 4 * 64 * 8]; // 32 KiB [kc][q][cm][8ci]
    const int blk = blockIdx.x;
    const int tid = threadIdx.x;

    if (blk >= BATCH * 65) {                      // ---- weight-pack blocks ----
        const int pb = blk - BATCH * 65;
        const int t = pb / 8;
        const int kc = pb % 8;
        const int co = tid;
        #pragma unroll
        for (int q = 0; q < 4; ++q) {
            u16 pk[8];
            #pragma unroll
            for (int j = 0; j < 8; ++j) {
                int ci = kc * 32 + q * 8 + j;
                pk[j] = f2bf(wH[((size_t)ci * COUT + co) * 9 + t]);
            }
            *(uint4*)(WPH + ((((size_t)t * 8 + kc) * 4 + q) * 256 + co) * 8) = *(uint4*)pk;
        }
        if (kc < 2) {
            #pragma unroll
            for (int q = 0; q < 4; ++q) {
                u16 pk[8];
                #pragma unroll
                for (int j = 0; j < 8; ++j) {
                    int cm = kc * 32 + q * 8 + j;
                    pk[j] = f2bf(wL[((size_t)cm * COUT + co) * 9 + t]);
                }
                *(uint4*)(WPL + ((((size_t)t * 2 + kc) * 4 + q) * 256 + co) * 8) = *(uint4*)pk;
            }
        }
        return;
    }

    // ---- input blocks ----
    const int b = blk / 65;
    const int y = blk % 65;
    u16* xrow  = Xt  + (size_t)(b * 65 + y) * XT_ROW;
    u16* x2row = X2t + (size_t)(b * 65 + y) * X2_ROW;
    if (y == H) {                                 // zero guard rows
        uint4 z = {0, 0, 0, 0};
        for (int i = tid; i < XT_ROW / 8; i += 256) *(uint4*)(xrow + i * 8) = z;
        for (int i = tid; i < X2_ROW / 8; i += 256) *(uint4*)(x2row + i * 8) = z;
        return;
    }

    // W1 -> LDS (8 B vector stores: 4 consecutive ci land in one granule half)
    #pragma unroll
    for (int i = 0; i < 16; ++i) {                // 4096 float4 / 256 threads
        int lin4 = i * 256 + tid;
        float4 v = ((const float4*)w1)[lin4];
        int lin = lin4 * 4;
        int cm = lin >> 8, ci = lin & 255;
        u16* dp = sW1 + (((size_t)(ci >> 3) * 64 + cm) * 8) + (ci & 7);
        ushort4 p;
        p.x = f2bf(v.x); p.y = f2bf(v.y); p.z = f2bf(v.z); p.w = f2bf(v.w);
        *(ushort4*)dp = p;
    }

    const int x = tid & 63, g0 = tid >> 6;
    #pragma unroll
    for (int gg = 0; gg < 8; ++gg) {
        const int s = gg * 4 + g0;                // s = kc*4+q, ci0 = s*8
        u16 pk[8];
        #pragma unroll
        for (int j = 0; j < 8; ++j)
            pk[j] = f2bf(inx[(((size_t)b * CIN + s * 8 + j) * H + y) * W + x]);
        uint4 v = *(uint4*)pk;
        *(uint4*)(xrow + ((size_t)s * 65 + x) * 8) = v;
        *(uint4*)(sX   + ((size_t)s * 64 + x) * 8) = v;
    }
    if (tid < 32) {                               // Xt x-guard granule
        uint4 z = {0, 0, 0, 0};
        *(uint4*)(xrow + ((size_t)tid * 65 + 64) * 8) = z;
    }
    if (tid < 8) {                                // X2t x-guard granule
        uint4 z = {0, 0, 0, 0};
        *(uint4*)(x2row + ((size_t)tid * 65 + 64) * 8) = z;
    }
    __syncthreads();

    // 1x1 bottleneck: M=64 cm x N=64 x, K=256.
    const int wv = tid >> 6, lane = tid & 63, l15 = lane & 15, q = lane >> 4;
    f32x4 acc[4] = {};
    #pragma unroll
    for (int kc = 0; kc < 8; ++kc) {
        bf16x8 bfr = *(const bf16x8*)(sX + ((size_t)(kc * 4 + q) * 64 + wv * 16 + l15) * 8);
        #pragma unroll
        for (int mi = 0; mi < 4; ++mi) {
            bf16x8 af = *(const bf16x8*)(sW1 + (((size_t)kc * 4 + q) * 64 + mi * 16 + l15) * 8);
            acc[mi] = __builtin_amdgcn_mfma_f32_16x16x32_bf16(af, bfr, acc[mi], 0, 0, 0);
        }
    }
    const int xx = wv * 16 + l15;
    #pragma unroll
    for (int mi = 0; mi < 4; ++mi) {              // C row cm = mi*16+q*4+r
        const int s = mi * 2 + (q >> 1);          // = (cm>>3)
        u16 pk[4];
        #pragma unroll
        for (int r = 0; r < 4; ++r)
            pk[r] = f2bf(acc[mi][r] + b1[mi * 16 + q * 4 + r]);
        *(ushort4*)(x2row + ((size_t)s * 65 + xx) * 8 + (q & 1) * 4) = *(ushort4*)&pk[0];
    }
}

// ---------------------------------------------------------------------------
// k_main: double-buffered LDS-staged phase GEMM, address-select masking.
// Grid 512 = (py, b, yP 0..31, coH). 4 waves = (rowR 2 x coQ 2).
// Step = (branch, kc, dy): stage next step's A (24KB) + B (2 rows, 8.2KB)
// while computing current from the other buffer.
// ROLLED step loop (was fully unrolled, ~36KB straight-line body per py
// variant vs 32KiB I$): runtime step decode, one copy of the body resident.
// ---------------------------------------------------------------------------
#define SA_G 1536                                 // A granules per buffer
#define SB_G 520                                  // B granules per buffer (8*65)

struct StepD { bool hi; int kc, dy, ky; };

__device__ __forceinline__ StepD step_decode(int c, int py) {
    StepD s;
    const int nh = 8 << py;                       // # hi steps (8 or 16)
    s.hi = c < nh;
    const int cc = s.hi ? c : c - nh;
    s.kc = cc >> py;                              // NR==1: cc ; NR==2: cc>>1
    s.dy = cc & py;                               // NR==1: 0  ; NR==2: cc&1
    s.ky = py ? (s.dy ? 0 : 2) : 1;
    return s;
}

__device__ __forceinline__ void stage_rt(const StepD st, u16* sAb, u16* sBb,
                                         const u16* __restrict__ Xt,
                                         const u16* __restrict__ X2t,
                                         const u16* __restrict__ WPH,
                                         const u16* __restrict__ WPL,
                                         int b, int y0, int coH, int wid, int lane) {
    const int kcn = st.hi ? 8 : 2;
    const u16* Wp = st.hi ? WPH : WPL;
    const u16* Xp = st.hi ? Xt : X2t;
    const size_t rowStr = st.hi ? (size_t)XT_ROW : (size_t)X2_ROW;
    // A: 24 segs of 64 granules; wave takes seg = i*4+wid
    #pragma unroll
    for (int i = 0; i < 6; ++i) {
        const int seg = i * 4 + wid;
        const int kx = seg >> 3, qq = (seg >> 1) & 3, h = seg & 1;
        const u16* src = Wp + ((((size_t)(st.ky * 3 + kx) * kcn + st.kc) * 4 + qq) * 256
                                + coH * 128 + h * 64 + lane) * 8;
        g2l16(src, sAb + ((size_t)((kx * 4 + qq) * 128 + h * 64)) * 8);
    }
    // B: 8 segs (2 rows x 4 q-chunks); wave wid stages q-chunk wid of each row
    #pragma unroll
    for (int i = 0; i < 2; ++i) {
        const u16* src = Xp + (size_t)(b * 65 + y0 + st.dy + i) * rowStr
                            + ((size_t)(st.kc * 4 + wid) * 65 + lane) * 8;
        g2l16(src, sBb + ((size_t)(i * 4 + wid) * 65) * 8);
    }
}

__device__ __forceinline__ void compute_rt(bool hi, const u16* sAb, const u16* sBb,
                                           const u16* zg,
                                           int rowR, int coQ, int q, int l15,
                                           const int* __restrict__ selE,
                                           const int* __restrict__ selO,
                                           f32x4 ce[4][4], f32x4 co_[4][4]) {
    const u16* bp = sBb + (((size_t)(rowR * 4 + q)) * 65 + l15) * 8;
    bf16x8 be[4], bo0[4], bo1[4];
    #pragma unroll
    for (int ni = 0; ni < 4; ++ni) {
        // address-select: deselected columns read the zero granule (broadcast)
        const bool kE = (selE[ni] != 0) == hi;
        const bool kO = (selO[ni] != 0) == hi;
        const u16* p0 = bp + ni * 128;
        be[ni]  = *(const bf16x8*)(kE ? p0 : zg);
        bo0[ni] = *(const bf16x8*)(kO ? p0 : zg);
        bo1[ni] = *(const bf16x8*)(kO ? p0 + 8 : zg);
    }
    const u16* ap = sAb + ((size_t)(q * 128 + coQ * 64 + l15)) * 8;
    #pragma unroll
    for (int mi = 0; mi < 4; ++mi) {              // kx=1 -> even cols
        bf16x8 a = *(const bf16x8*)(ap + (1 * 512 + mi * 16) * 8);
        #pragma unroll
        for (int ni = 0; ni < 4; ++ni)
            ce[mi][ni] = __builtin_amdgcn_mfma_f32_16x16x32_bf16(a, be[ni], ce[mi][ni], 0, 0, 0);
    }
    #pragma unroll
    for (int mi = 0; mi < 4; ++mi) {              // kx=2 -> odd cols, dx=0
        bf16x8 a = *(const bf16x8*)(ap + (2 * 512 + mi * 16) * 8);
        #pragma unroll
        for (int ni = 0; ni < 4; ++ni)
            co_[mi][ni] = __builtin_amdgcn_mfma_f32_16x16x32_bf16(a, bo0[ni], co_[mi][ni], 0, 0, 0);
    }
    #pragma unroll
    for (int mi = 0; mi < 4; ++mi) {              // kx=0 -> odd cols, dx=1
        bf16x8 a = *(const bf16x8*)(ap + (mi * 16) * 8);
        #pragma unroll
        for (int ni = 0; ni < 4; ++ni)
            co_[mi][ni] = __builtin_amdgcn_mfma_f32_16x16x32_bf16(a, bo1[ni], co_[mi][ni], 0, 0, 0);
    }
}

__global__ __launch_bounds__(256, 2) void k_main(const u16* __restrict__ Xt,
                                                 const u16* __restrict__ X2t,
                                                 const u16* __restrict__ WPH,
                                                 const u16* __restrict__ WPL,
                                                 const float* __restrict__ bH,
                                                 const float* __restrict__ bL,
                                                 const float* __restrict__ mask,
                                                 float* __restrict__ out) {
    __shared__ __align__(16) u16 sA[2][SA_G * 8]; // 2 x 24576 B
    __shared__ __align__(16) u16 sB[2][SB_G * 8]; // 2 x  8320 B
    __shared__ __align__(16) u16 sZ[8];           // 16 B zero granule

    const int blk = blockIdx.x;
    const int coH = blk & 1;
    const int yP  = (blk >> 1) & 31;
    const int b   = (blk >> 6) & 3;
    const int py  = blk >> 8;
    const int y0  = yP * 2;

    const int tid = threadIdx.x;
    const int wid = tid >> 6, lane = tid & 63, l15 = lane & 15, q = lane >> 4;
    const int rowR = wid >> 1, coQ = wid & 1;
    const int oy = 2 * (y0 + rowR) + py;

    // per-column branch selects (mask is exactly 0/1)
    int selE[4], selO[4];
    const float* mrow = mask + ((size_t)b * HO + oy) * WO;
    #pragma unroll
    for (int ni = 0; ni < 4; ++ni) {
        float2 mm = *(const float2*)(mrow + 2 * (ni * 16 + l15));
        selE[ni] = (mm.x != 0.f);
        selO[ni] = (mm.y != 0.f);
    }

    if (tid < 16) {                               // zero B x-guard granules
        uint4 z = {0, 0, 0, 0};
        *(uint4*)(sB[tid >> 3] + (((size_t)(tid & 7)) * 65 + 64) * 8) = z;
    }
    if (tid == 16) *(uint4*)sZ = (uint4){0, 0, 0, 0};

    f32x4 ce[4][4] = {}, co_[4][4] = {};

    const int NS = 10 << py;                      // 10 (py=0) or 20 (py=1)
    stage_rt(step_decode(0, py), sA[0], sB[0], Xt, X2t, WPH, WPL, b, y0, coH, wid, lane);
    __syncthreads();

    u16* cA = sA[0]; u16* cB = sB[0];
    u16* nA = sA[1]; u16* nB = sB[1];
    #pragma unroll 1
    for (int c = 0; c < NS - 1; ++c) {
        stage_rt(step_decode(c + 1, py), nA, nB, Xt, X2t, WPH, WPL, b, y0, coH, wid, lane);
        compute_rt(c < (8 << py), cA, cB, sZ, rowR, coQ, q, l15, selE, selO, ce, co_);
        __syncthreads();                          // drains vmcnt -> nA/nB ready
        u16* t;
        t = cA; cA = nA; nA = t;
        t = cB; cB = nB; nB = t;
    }
    compute_rt((NS - 1) < (8 << py), cA, cB, sZ, rowR, coQ, q, l15, selE, selO, ce, co_);

    // ---- epilogue: add selected bias, float2 full-density stores ----
    #pragma unroll
    for (int mi = 0; mi < 4; ++mi) {
        const int cob = coH * 128 + coQ * 64 + mi * 16 + q * 4;
        float bh[4], bl[4];
        #pragma unroll
        for (int r = 0; r < 4; ++r) { bh[r] = bH[cob + r]; bl[r] = bL[cob + r]; }
        #pragma unroll
        for (int r = 0; r < 4; ++r) {
            float* orow = out + (((size_t)b * COUT + cob + r) * HO + oy) * WO;
            #pragma unroll
            for (int ni = 0; ni < 4; ++ni) {
                const int x = ni * 16 + l15;
                float2 v;
                v.x = ce[mi][ni][r]  + (selE[ni] ? bh[r] : bl[r]);
                v.y = co_[mi][ni][r] + (selO[ni] ? bh[r] : bl[r]);
                *(float2*)(orow + 2 * x) = v;
            }
        }
    }
}

// ---------------------------------------------------------------------------
extern "C" void kernel_launch(void* const* d_in, const int* in_sizes, int n_in,
                              void* d_out, int out_size, void* d_ws, size_t ws_size,
                              hipStream_t stream) {
    const float* inx    = (const float*)d_in[0];
    const float* mask   = (const float*)d_in[1];
    // d_in[2] = inv_mask (unused: mask is exactly 0/1)
    const float* w_high = (const float*)d_in[3];
    const float* b_high = (const float*)d_in[4];
    const float* w_low1 = (const float*)d_in[5];
    const float* b_low1 = (const float*)d_in[6];
    const float* w_low2 = (const float*)d_in[7];
    const float* b_low2 = (const float*)d_in[8];
    float* out = (float*)d_out;

    char* ws = (char*)d_ws;
    u16* Xt  = (u16*)(ws);                 //  8,652,800 B
    u16* X2t = (u16*)(ws + 8652800);       //  2,163,200 B
    u16* WPH = (u16*)(ws + 10816000);      //  1,179,648 B
    u16* WPL = (u16*)(ws + 11995648);      //    294,912 B  (total ~12.3 MiB)

    k_prep<<<BATCH * 65 + 72, 256, 0, stream>>>(inx, w_low1, b_low1, w_high, w_low2,
                                                Xt, X2t, WPH, WPL);
    k_main<<<512, 256, 0, stream>>>(Xt, X2t, WPH, WPL, b_high, b_low2, mask, out);
}

// Round 3
// 125.354 us; speedup vs baseline: 1.0103x; 1.0103x over previous
//
#include <hip/hip_runtime.h>
#include <cstdint>
#include <cstddef>

#define CIN   256
#define COUT  256
#define CMID  64
#define H     64
#define W     64
#define HO    128
#define WO    128
#define BATCH 4

typedef unsigned short u16;
typedef unsigned int   u32;
typedef __attribute__((ext_vector_type(8))) __bf16 bf16x8;
typedef __attribute__((ext_vector_type(4))) float f32x4;

// Packed layouts (granule = 8 bf16 = 16 B, lane-contiguous):
//   Xt [b][y(65)][s=kc*4+q (32)][x(65)][8ci]   row = 16640 u16
//   X2t[b][y(65)][s=kc2*4+q (8)][x(65)][8cm]   row = 4160 u16
//   WPH[t(9)][kc(8)][q(4)][co(256)][8ci]
//   WPL[t(9)][kc2(2)][q(4)][co(256)][8cm]
// y==64 zero guard row; x==64 zero guard granule.
#define XT_ROW  16640
#define X2_ROW  4160

#define AS1 __attribute__((address_space(1)))
#define AS3 __attribute__((address_space(3)))

// global->LDS direct 16B copy; LDS dst is wave-uniform base, HW adds lane*16.
__device__ __forceinline__ void g2l16(const void* g, const void* l) {
    __builtin_amdgcn_global_load_lds((const AS1 u32*)(uintptr_t)g,
                                     (AS3 u32*)(u32)(uintptr_t)l, 16, 0, 0);
}

__device__ __forceinline__ u16 f2bf(float f) {
    u32 u = __builtin_bit_cast(u32, f);
    u += 0x7fffu + ((u >> 16) & 1u);          // RNE
    return (u16)(u >> 16);
}

// ---------------------------------------------------------------------------
// Fused prep (grid 332 = 260 input blocks + 72 weight-pack blocks).
// ---------------------------------------------------------------------------
__global__ __launch_bounds__(256) void k_prep(const float* __restrict__ inx,
                                              const float* __restrict__ w1,
                                              const float* __restrict__ b1,
                                              const float* __restrict__ wH,
                                              const float* __restrict__ wL,
                                              u16* __restrict__ Xt,
                                              u16* __restrict__ X2t,
                                              u16* __restrict__ WPH,
                                              u16* __restrict__ WPL) {
    __shared__ __align__(16) u16 sX[32 * 64 * 8];     // 32 KiB [s][x][8ci]
    __shared__ __align__(16) u16 sW1[8 * 4 * 64 * 8]; // 32 KiB [kc][q][cm][8ci]
    const int blk = blockIdx.x;
    const int tid = threadIdx.x;

    if (blk >= BATCH * 65) {                      // ---- weight-pack blocks ----
        const int pb = blk - BATCH * 65;
        const int t = pb / 8;
        const int kc = pb % 8;
        const int co = tid;
        #pragma unroll
        for (int q = 0; q < 4; ++q) {
            u16 pk[8];
            #pragma unroll
            for (int j = 0; j < 8; ++j) {
                int ci = kc * 32 + q * 8 + j;
                pk[j] = f2bf(wH[((size_t)ci * COUT + co) * 9 + t]);
            }
            *(uint4*)(WPH + ((((size_t)t * 8 + kc) * 4 + q) * 256 + co) * 8) = *(uint4*)pk;
        }
        if (kc < 2) {
            #pragma unroll
            for (int q = 0; q < 4; ++q) {
                u16 pk[8];
                #pragma unroll
                for (int j = 0; j < 8; ++j) {
                    int cm = kc * 32 + q * 8 + j;
                    pk[j] = f2bf(wL[((size_t)cm * COUT + co) * 9 + t]);
                }
                *(uint4*)(WPL + ((((size_t)t * 2 + kc) * 4 + q) * 256 + co) * 8) = *(uint4*)pk;
            }
        }
        return;
    }

    // ---- input blocks ----
    const int b = blk / 65;
    const int y = blk % 65;
    u16* xrow  = Xt  + (size_t)(b * 65 + y) * XT_ROW;
    u16* x2row = X2t + (size_t)(b * 65 + y) * X2_ROW;
    if (y == H) {                                 // zero guard rows
        uint4 z = {0, 0, 0, 0};
        for (int i = tid; i < XT_ROW / 8; i += 256) *(uint4*)(xrow + i * 8) = z;
        for (int i = tid; i < X2_ROW / 8; i += 256) *(uint4*)(x2row + i * 8) = z;
        return;
    }

    // W1 -> LDS (8 B vector stores: 4 consecutive ci land in one granule half)
    #pragma unroll
    for (int i = 0; i < 16; ++i) {                // 4096 float4 / 256 threads
        int lin4 = i * 256 + tid;
        float4 v = ((const float4*)w1)[lin4];
        int lin = lin4 * 4;
        int cm = lin >> 8, ci = lin & 255;
        u16* dp = sW1 + (((size_t)(ci >> 3) * 64 + cm) * 8) + (ci & 7);
        ushort4 p;
        p.x = f2bf(v.x); p.y = f2bf(v.y); p.z = f2bf(v.z); p.w = f2bf(v.w);
        *(ushort4*)dp = p;
    }

    const int x = tid & 63, g0 = tid >> 6;
    #pragma unroll
    for (int gg = 0; gg < 8; ++gg) {
        const int s = gg * 4 + g0;                // s = kc*4+q, ci0 = s*8
        u16 pk[8];
        #pragma unroll
        for (int j = 0; j < 8; ++j)
            pk[j] = f2bf(inx[(((size_t)b * CIN + s * 8 + j) * H + y) * W + x]);
        uint4 v = *(uint4*)pk;
        *(uint4*)(xrow + ((size_t)s * 65 + x) * 8) = v;
        *(uint4*)(sX   + ((size_t)s * 64 + x) * 8) = v;
    }
    if (tid < 32) {                               // Xt x-guard granule
        uint4 z = {0, 0, 0, 0};
        *(uint4*)(xrow + ((size_t)tid * 65 + 64) * 8) = z;
    }
    if (tid < 8) {                                // X2t x-guard granule
        uint4 z = {0, 0, 0, 0};
        *(uint4*)(x2row + ((size_t)tid * 65 + 64) * 8) = z;
    }
    __syncthreads();

    // 1x1 bottleneck: M=64 cm x N=64 x, K=256.
    const int wv = tid >> 6, lane = tid & 63, l15 = lane & 15, q = lane >> 4;
    f32x4 acc[4] = {};
    #pragma unroll
    for (int kc = 0; kc < 8; ++kc) {
        bf16x8 bfr = *(const bf16x8*)(sX + ((size_t)(kc * 4 + q) * 64 + wv * 16 + l15) * 8);
        #pragma unroll
        for (int mi = 0; mi < 4; ++mi) {
            bf16x8 af = *(const bf16x8*)(sW1 + (((size_t)kc * 4 + q) * 64 + mi * 16 + l15) * 8);
            acc[mi] = __builtin_amdgcn_mfma_f32_16x16x32_bf16(af, bfr, acc[mi], 0, 0, 0);
        }
    }
    const int xx = wv * 16 + l15;
    #pragma unroll
    for (int mi = 0; mi < 4; ++mi) {              // C row cm = mi*16+q*4+r
        const int s = mi * 2 + (q >> 1);          // = (cm>>3)
        u16 pk[4];
        #pragma unroll
        for (int r = 0; r < 4; ++r)
            pk[r] = f2bf(acc[mi][r] + b1[mi * 16 + q * 4 + r]);
        *(ushort4*)(x2row + ((size_t)s * 65 + xx) * 8 + (q & 1) * 4) = *(ushort4*)&pk[0];
    }
}

// ---------------------------------------------------------------------------
// k_main: double-buffered LDS-staged phase GEMM, address-select masking.
// Grid 512 = (py, b, yP 0..31, coH). 4 waves = (rowR 2 x coQ 2).
// Step = (branch, kc, dy): stage next step's A (24KB) + B (2 rows, 8.2KB)
// while computing current from the other buffer.
// T4 counted-vmcnt pipeline: per iter, issue stage(c+1) (8 loads/wave),
// s_waitcnt vmcnt(8) (waits ONLY stage(c); c+1's loads stay in flight
// across the barrier), s_barrier, compute(c), s_barrier (WAR guard).
// Never drains vmcnt to 0 in the main loop (was: __syncthreads ->
// s_waitcnt vmcnt(0) -> ~200-550 cyc stall per step on L3/HBM misses).
// ---------------------------------------------------------------------------
#define SA_G 1536                                 // A granules per buffer
#define SB_G 520                                  // B granules per buffer (8*65)

struct StepD { bool hi; int kc, dy, ky; };

__device__ __forceinline__ StepD step_decode(int c, int py) {
    StepD s;
    const int nh = 8 << py;                       // # hi steps (8 or 16)
    s.hi = c < nh;
    const int cc = s.hi ? c : c - nh;
    s.kc = cc >> py;                              // NR==1: cc ; NR==2: cc>>1
    s.dy = cc & py;                               // NR==1: 0  ; NR==2: cc&1
    s.ky = py ? (s.dy ? 0 : 2) : 1;
    return s;
}

__device__ __forceinline__ void stage_rt(const StepD st, u16* sAb, u16* sBb,
                                         const u16* __restrict__ Xt,
                                         const u16* __restrict__ X2t,
                                         const u16* __restrict__ WPH,
                                         const u16* __restrict__ WPL,
                                         int b, int y0, int coH, int wid, int lane) {
    const int kcn = st.hi ? 8 : 2;
    const u16* Wp = st.hi ? WPH : WPL;
    const u16* Xp = st.hi ? Xt : X2t;
    const size_t rowStr = st.hi ? (size_t)XT_ROW : (size_t)X2_ROW;
    // A: 24 segs of 64 granules; wave takes seg = i*4+wid  (6 loads)
    #pragma unroll
    for (int i = 0; i < 6; ++i) {
        const int seg = i * 4 + wid;
        const int kx = seg >> 3, qq = (seg >> 1) & 3, h = seg & 1;
        const u16* src = Wp + ((((size_t)(st.ky * 3 + kx) * kcn + st.kc) * 4 + qq) * 256
                                + coH * 128 + h * 64 + lane) * 8;
        g2l16(src, sAb + ((size_t)((kx * 4 + qq) * 128 + h * 64)) * 8);
    }
    // B: 8 segs (2 rows x 4 q-chunks); wave wid stages q-chunk wid (2 loads)
    #pragma unroll
    for (int i = 0; i < 2; ++i) {
        const u16* src = Xp + (size_t)(b * 65 + y0 + st.dy + i) * rowStr
                            + ((size_t)(st.kc * 4 + wid) * 65 + lane) * 8;
        g2l16(src, sBb + ((size_t)(i * 4 + wid) * 65) * 8);
    }
}   // exactly 8 global_load_lds per wave per call -> vmcnt counts in 8s

__device__ __forceinline__ void compute_rt(bool hi, const u16* sAb, const u16* sBb,
                                           const u16* zg,
                                           int rowR, int coQ, int q, int l15,
                                           const int* __restrict__ selE,
                                           const int* __restrict__ selO,
                                           f32x4 ce[4][4], f32x4 co_[4][4]) {
    const u16* bp = sBb + (((size_t)(rowR * 4 + q)) * 65 + l15) * 8;
    bf16x8 be[4], bo0[4], bo1[4];
    #pragma unroll
    for (int ni = 0; ni < 4; ++ni) {
        // address-select: deselected columns read the zero granule (broadcast)
        const bool kE = (selE[ni] != 0) == hi;
        const bool kO = (selO[ni] != 0) == hi;
        const u16* p0 = bp + ni * 128;
        be[ni]  = *(const bf16x8*)(kE ? p0 : zg);
        bo0[ni] = *(const bf16x8*)(kO ? p0 : zg);
        bo1[ni] = *(const bf16x8*)(kO ? p0 + 8 : zg);
    }
    const u16* ap = sAb + ((size_t)(q * 128 + coQ * 64 + l15)) * 8;
    #pragma unroll
    for (int mi = 0; mi < 4; ++mi) {              // kx=1 -> even cols
        bf16x8 a = *(const bf16x8*)(ap + (1 * 512 + mi * 16) * 8);
        #pragma unroll
        for (int ni = 0; ni < 4; ++ni)
            ce[mi][ni] = __builtin_amdgcn_mfma_f32_16x16x32_bf16(a, be[ni], ce[mi][ni], 0, 0, 0);
    }
    #pragma unroll
    for (int mi = 0; mi < 4; ++mi) {              // kx=2 -> odd cols, dx=0
        bf16x8 a = *(const bf16x8*)(ap + (2 * 512 + mi * 16) * 8);
        #pragma unroll
        for (int ni = 0; ni < 4; ++ni)
            co_[mi][ni] = __builtin_amdgcn_mfma_f32_16x16x32_bf16(a, bo0[ni], co_[mi][ni], 0, 0, 0);
    }
    #pragma unroll
    for (int mi = 0; mi < 4; ++mi) {              // kx=0 -> odd cols, dx=1
        bf16x8 a = *(const bf16x8*)(ap + (mi * 16) * 8);
        #pragma unroll
        for (int ni = 0; ni < 4; ++ni)
            co_[mi][ni] = __builtin_amdgcn_mfma_f32_16x16x32_bf16(a, bo1[ni], co_[mi][ni], 0, 0, 0);
    }
}

__global__ __launch_bounds__(256, 2) void k_main(const u16* __restrict__ Xt,
                                                 const u16* __restrict__ X2t,
                                                 const u16* __restrict__ WPH,
                                                 const u16* __restrict__ WPL,
                                                 const float* __restrict__ bH,
                                                 const float* __restrict__ bL,
                                                 const float* __restrict__ mask,
                                                 float* __restrict__ out) {
    __shared__ __align__(16) u16 sA[2][SA_G * 8]; // 2 x 24576 B
    __shared__ __align__(16) u16 sB[2][SB_G * 8]; // 2 x  8320 B
    __shared__ __align__(16) u16 sZ[8];           // 16 B zero granule

    const int blk = blockIdx.x;
    const int coH = blk & 1;
    const int yP  = (blk >> 1) & 31;
    const int b   = (blk >> 6) & 3;
    const int py  = blk >> 8;
    const int y0  = yP * 2;

    const int tid = threadIdx.x;
    const int wid = tid >> 6, lane = tid & 63, l15 = lane & 15, q = lane >> 4;
    const int rowR = wid >> 1, coQ = wid & 1;
    const int oy = 2 * (y0 + rowR) + py;

    // per-column branch selects (mask is exactly 0/1)
    int selE[4], selO[4];
    const float* mrow = mask + ((size_t)b * HO + oy) * WO;
    #pragma unroll
    for (int ni = 0; ni < 4; ++ni) {
        float2 mm = *(const float2*)(mrow + 2 * (ni * 16 + l15));
        selE[ni] = (mm.x != 0.f);
        selO[ni] = (mm.y != 0.f);
    }

    if (tid < 16) {                               // zero B x-guard granules
        uint4 z = {0, 0, 0, 0};
        *(uint4*)(sB[tid >> 3] + (((size_t)(tid & 7)) * 65 + 64) * 8) = z;
    }
    if (tid == 16) *(uint4*)sZ = (uint4){0, 0, 0, 0};

    f32x4 ce[4][4] = {}, co_[4][4] = {};

    const int NS = 10 << py;                      // 10 (py=0) or 20 (py=1)
    stage_rt(step_decode(0, py), sA[0], sB[0], Xt, X2t, WPH, WPL, b, y0, coH, wid, lane);
    // guard-granule ds_writes must land before first barrier releases readers
    asm volatile("s_waitcnt lgkmcnt(0)" ::: "memory");

    u16* cA = sA[0]; u16* cB = sB[0];
    u16* nA = sA[1]; u16* nB = sB[1];
    #pragma unroll 1
    for (int c = 0; c < NS - 1; ++c) {
        stage_rt(step_decode(c + 1, py), nA, nB, Xt, X2t, WPH, WPL, b, y0, coH, wid, lane);
        // wait stage(c) only; stage(c+1)'s 8 loads stay in flight across barrier
        asm volatile("s_waitcnt vmcnt(8)" ::: "memory");
        __builtin_amdgcn_sched_barrier(0);
        __builtin_amdgcn_s_barrier();             // all waves' stage(c) visible
        __builtin_amdgcn_sched_barrier(0);
        compute_rt(c < (8 << py), cA, cB, sZ, rowR, coQ, q, l15, selE, selO, ce, co_);
        __builtin_amdgcn_sched_barrier(0);
        __builtin_amdgcn_s_barrier();             // readers done before buf reuse (WAR)
        u16* t;
        t = cA; cA = nA; nA = t;
        t = cB; cB = nB; nB = t;
    }
    asm volatile("s_waitcnt vmcnt(0)" ::: "memory");  // drain last stage (epilogue only)
    __builtin_amdgcn_sched_barrier(0);
    __builtin_amdgcn_s_barrier();
    compute_rt((NS - 1) < (8 << py), cA, cB, sZ, rowR, coQ, q, l15, selE, selO, ce, co_);

    // ---- epilogue: add selected bias, float2 full-density stores ----
    #pragma unroll
    for (int mi = 0; mi < 4; ++mi) {
        const int cob = coH * 128 + coQ * 64 + mi * 16 + q * 4;
        float bh[4], bl[4];
        #pragma unroll
        for (int r = 0; r < 4; ++r) { bh[r] = bH[cob + r]; bl[r] = bL[cob + r]; }
        #pragma unroll
        for (int r = 0; r < 4; ++r) {
            float* orow = out + (((size_t)b * COUT + cob + r) * HO + oy) * WO;
            #pragma unroll
            for (int ni = 0; ni < 4; ++ni) {
                const int x = ni * 16 + l15;
                float2 v;
                v.x = ce[mi][ni][r]  + (selE[ni] ? bh[r] : bl[r]);
                v.y = co_[mi][ni][r] + (selO[ni] ? bh[r] : bl[r]);
                *(float2*)(orow + 2 * x) = v;
            }
        }
    }
}

// ---------------------------------------------------------------------------
extern "C" void kernel_launch(void* const* d_in, const int* in_sizes, int n_in,
                              void* d_out, int out_size, void* d_ws, size_t ws_size,
                              hipStream_t stream) {
    const float* inx    = (const float*)d_in[0];
    const float* mask   = (const float*)d_in[1];
    // d_in[2] = inv_mask (unused: mask is exactly 0/1)
    const float* w_high = (const float*)d_in[3];
    const float* b_high = (const float*)d_in[4];
    const float* w_low1 = (const float*)d_in[5];
    const float* b_low1 = (const float*)d_in[6];
    const float* w_low2 = (const float*)d_in[7];
    const float* b_low2 = (const float*)d_in[8];
    float* out = (float*)d_out;

    char* ws = (char*)d_ws;
    u16* Xt  = (u16*)(ws);                 //  8,652,800 B
    u16* X2t = (u16*)(ws + 8652800);       //  2,163,200 B
    u16* WPH = (u16*)(ws + 10816000);      //  1,179,648 B
    u16* WPL = (u16*)(ws + 11995648);      //    294,912 B  (total ~12.3 MiB)

    k_prep<<<BATCH * 65 + 72, 256, 0, stream>>>(inx, w_low1, b_low1, w_high, w_low2,
                                                Xt, X2t, WPH, WPL);
    k_main<<<512, 256, 0, stream>>>(Xt, X2t, WPH, WPL, b_high, b_low2, mask, out);
}